// Round 3
// baseline (7014.125 us; speedup 1.0000x reference)
//
#include <hip/hip_runtime.h>
#include <math.h>

#define T 512
#define D 128
#define H 512
#define EMB 256
#define Z4 2048          // 4*H
#define NWG 16           // workgroups in recurrent kernels
#define SLICE 32         // hidden units per wg (H/NWG)
#define NTH 512          // threads per wg

typedef unsigned long long u64;
typedef unsigned int u32;

// ---- device-global scratch (tags zeroed by k_xp each call) ----
__device__ float g_xp[T * Z4];        // encoder input projections + bh
__device__ u64 g_he[2][H];            // encoder h, packed {tag,val}, slot = tag&1
__device__ u64 g_hd[2][H];            // decoder h, packed
__device__ u64 g_xq[2][NWG][D];       // decoder x partials, packed
__device__ float g_hd0[H];            // decoder initial hidden

__device__ __forceinline__ u64 aload64(const u64* p) {
    return __hip_atomic_load(p, __ATOMIC_RELAXED, __HIP_MEMORY_SCOPE_AGENT);
}
__device__ __forceinline__ void astore64(u64* p, u64 v) {
    __hip_atomic_store(p, v, __ATOMIC_RELAXED, __HIP_MEMORY_SCOPE_AGENT);
}
__device__ __forceinline__ u64 pack2(u32 tag, float v) {
    return ((u64)tag << 32) | (u64)__float_as_uint(v);
}
__device__ __forceinline__ float lo_f(u64 v) { return __uint_as_float((u32)v); }
__device__ __forceinline__ u32 hi_t(u64 v) { return (u32)(v >> 32); }

// fast gates (approx rcp ~1ulp; clamped so exp can't overflow)
__device__ __forceinline__ float fsigm(float x) {
    x = fminf(fmaxf(x, -30.f), 30.f);
    return __builtin_amdgcn_rcpf(1.f + __expf(-x));
}
__device__ __forceinline__ float ftanh(float x) {
    x = fminf(fmaxf(x, -15.f), 15.f);
    const float e = __expf(2.f * x);
    return (e - 1.f) * __builtin_amdgcn_rcpf(e + 1.f);
}

// ---- K1: XP = trajectory @ enc_Wi + enc_bh (parallel) + tag-array zeroing ----
#define TT 16
__global__ __launch_bounds__(256, 1)
void k_xp(const float* __restrict__ traj, const float* __restrict__ Wi,
          const float* __restrict__ bh) {
    const int tid = threadIdx.x;
    if (blockIdx.y == 0) {
        const int fid = blockIdx.x * 256 + tid;       // 0..2047
        if (fid < H) {
            g_he[0][fid] = 0ull; g_he[1][fid] = 0ull;
            g_hd[0][fid] = 0ull; g_hd[1][fid] = 0ull;
        }
        u64* xqf = &g_xq[0][0][0];                    // 2*NWG*D = 4096 entries
        xqf[fid] = 0ull; xqf[fid + 2048] = 0ull;
    }
    const int jc = blockIdx.x;     // 0..7 column chunk
    const int t0 = blockIdx.y * TT;
    const int j  = jc * 256 + tid;

    __shared__ float tl[TT * D];
#pragma unroll
    for (int r = 0; r < (TT * D) / 256; ++r)
        tl[r * 256 + tid] = traj[t0 * D + r * 256 + tid];
    __syncthreads();

    float acc[TT];
#pragma unroll
    for (int tt = 0; tt < TT; ++tt) acc[tt] = 0.f;
    for (int i = 0; i < D; ++i) {
        const float wv = Wi[i * Z4 + j];
#pragma unroll
        for (int tt = 0; tt < TT; ++tt) acc[tt] += tl[tt * D + i] * wv;
    }
    const float bv = bh[j];
#pragma unroll
    for (int tt = 0; tt < TT; ++tt)
        g_xp[(t0 + tt) * Z4 + j] = acc[tt] + bv;
}

// thread mapping shared by k_enc/k_dec:
//   c = tid>>2 (column 0..127), p = tid&3 (row part: Wh rows [128p,128p+128))
//   u = c>>2 (unit 0..31), gt = c&3 (gate i/f/g/o)
//   global z column = gt*H + w*SLICE + u
// column's 4 partials are lanes 4c..4c+3 (same wave); unit's 4 gates are
// lanes lb+{0,4,8,12} (same wave) -> pure shuffle reduction, no LDS.

// ---- K2: encoder recurrence ----
__global__ __launch_bounds__(NTH, 2)
void k_enc(const float* __restrict__ Wh) {
    const int w   = blockIdx.x;
    const int tid = threadIdx.x;
    const int c   = tid >> 2;
    const int p   = tid & 3;
    const int u   = c >> 2;
    const int gt  = c & 3;
    const int k0  = w * SLICE;
    const int col = gt * H + k0 + u;
    const int l   = tid & 63;
    const int lb  = (l & ~15) + (l & 3);

    float wh[128];
#pragma unroll
    for (int q = 0; q < 128; ++q)
        wh[q] = Wh[(p * 128 + q) * Z4 + col];

    __shared__ float hl[2][4][132];   // parity double-buffer, padded

    float creg = 0.f;

    for (int t = 0; t < T; ++t) {
        const int par = t & 1;
        // issued before the poll: latency hides under the spin
        float xpv = (p == 0) ? g_xp[t * Z4 + col] : 0.f;

        if (t > 0) {
            const u32 want = (u32)t;
            const u64* hp = &g_he[par][tid];
            u64 a = aload64(hp);
            for (;;) { u64 b = aload64(hp); if (hi_t(a) == want) break; a = b; }
            hl[par][tid >> 7][tid & 127] = lo_f(a);
        } else {
            hl[par][tid >> 7][tid & 127] = 0.f;
        }
        __syncthreads();   // the ONLY barrier per step (parity dbuf removes WAR)

        float acc = xpv;
#pragma unroll
        for (int q4 = 0; q4 < 32; ++q4) {
            const float4 hv = *reinterpret_cast<const float4*>(&hl[par][p][q4 * 4]);
            acc += hv.x * wh[q4 * 4 + 0] + hv.y * wh[q4 * 4 + 1] +
                   hv.z * wh[q4 * 4 + 2] + hv.w * wh[q4 * 4 + 3];
        }
        acc += __shfl_xor(acc, 1);
        acc += __shfl_xor(acc, 2);
        const float zi = __shfl(acc, lb + 0);
        const float zf = __shfl(acc, lb + 4);
        const float zg = __shfl(acc, lb + 8);
        const float zo = __shfl(acc, lb + 12);
        const float cn = fsigm(zf) * creg + fsigm(zi) * ftanh(zg);
        creg = cn;
        const float hn = fsigm(zo) * ftanh(cn);
        if ((tid & 15) == 0)
            astore64(&g_he[(t + 1) & 1][k0 + (tid >> 4)], pack2((u32)(t + 1), hn));
    }
}

// ---- K3: embedding + decoder init (1 wg) ----
__global__ __launch_bounds__(256, 1)
void k_emb(const float* __restrict__ embW, const float* __restrict__ embB,
           const float* __restrict__ diW, const float* __restrict__ diB,
           float* __restrict__ out) {
    const int tid = threadIdx.x;
    __shared__ float h_l[H];
    __shared__ float e_l[EMB];
#pragma unroll
    for (int r = 0; r < H / 256; ++r)
        h_l[r * 256 + tid] = lo_f(g_he[0][r * 256 + tid]);   // tag 512, slot 0
    __syncthreads();

    float acc = embB[tid];
    for (int i = 0; i < H; ++i)
        acc += h_l[i] * embW[i * EMB + tid];
    e_l[tid] = acc;
    out[T * D + tid] = acc;            // embedding output
    __syncthreads();

#pragma unroll
    for (int r = 0; r < H / 256; ++r) {
        const int k = r * 256 + tid;
        float a2 = diB[k];
        for (int e = 0; e < EMB; ++e)
            a2 += e_l[e] * diW[e * H + k];
        g_hd0[k] = a2;
    }
}

// ---- K4: decoder recurrence + per-step output ----
__global__ __launch_bounds__(NTH, 2)
void k_dec(const float* __restrict__ Wi, const float* __restrict__ Wh,
           const float* __restrict__ bh, const float* __restrict__ Wt,
           const float* __restrict__ bt, float* __restrict__ out) {
    const int w   = blockIdx.x;
    const int tid = threadIdx.x;
    const int c   = tid >> 2;
    const int p   = tid & 3;       // Wh rows [128p,+128), Wi rows [32p,+32)
    const int u   = c >> 2;
    const int gt  = c & 3;
    const int k0  = w * SLICE;
    const int col = gt * H + k0 + u;
    const int l   = tid & 63;
    const int lb  = (l & ~15) + (l & 3);
    const int d   = tid & 127;     // x dim for poll/px
    const int a4  = tid >> 7;      // x-partial slot group 0..3

    float wh[128], wx[32];
#pragma unroll
    for (int q = 0; q < 32; ++q)
        wx[q] = Wi[(p * 32 + q) * Z4 + col];
#pragma unroll
    for (int q = 0; q < 128; ++q)
        wh[q] = Wh[(p * 128 + q) * Z4 + col];
    const float bhz = (p == 0) ? bh[col] : 0.f;

    __shared__ float hl[2][4][132];      // h, parity dbuf, padded
    __shared__ float zxp[2][4][4][36];   // x partials [par][a4][part][idx], padded
    __shared__ float hs_lds[SLICE];

    float creg = 0.f;

    for (int s = 0; s < T; ++s) {
        const int par = s & 1;
        // prefetch this step's output-weight rows (independent of h)
        float wpre[SLICE];
        float btv = 0.f;
        if (tid < D) {
#pragma unroll
            for (int kk = 0; kk < SLICE; ++kk)
                wpre[kk] = Wt[((size_t)s * H + k0 + kk) * D + d];
            if (w == 0) btv = bt[s * D + d];
        }

        if (s > 0) {
            const u32 want = (u32)s;
            const u64* hp = &g_hd[par][tid];
            u64 a = aload64(hp);
            for (;;) { u64 b = aload64(hp); if (hi_t(a) == want) break; a = b; }
            hl[par][tid >> 7][tid & 127] = lo_f(a);
        } else {
            hl[par][tid >> 7][tid & 127] = g_hd0[tid];
        }
        __syncthreads();                       // (A)

        float acc = bhz;
#pragma unroll
        for (int q4 = 0; q4 < 32; ++q4) {
            const float4 hv = *reinterpret_cast<const float4*>(&hl[par][p][q4 * 4]);
            acc += hv.x * wh[q4 * 4 + 0] + hv.y * wh[q4 * 4 + 1] +
                   hv.z * wh[q4 * 4 + 2] + hv.w * wh[q4 * 4 + 3];
        }

        // x partials: produced ~with h, but only needed now -> near-zero wait
        if (s > 0) {
            const u32 want = (u32)s;
            const u64* x0 = &g_xq[par][a4 * 4 + 0][d];
            const u64* x1 = &g_xq[par][a4 * 4 + 1][d];
            const u64* x2 = &g_xq[par][a4 * 4 + 2][d];
            const u64* x3 = &g_xq[par][a4 * 4 + 3][d];
            u64 v0, v1, v2, v3;
            for (;;) {
                v0 = aload64(x0); v1 = aload64(x1);
                v2 = aload64(x2); v3 = aload64(x3);
                if ((hi_t(v0) == want) & (hi_t(v1) == want) &
                    (hi_t(v2) == want) & (hi_t(v3) == want)) break;
            }
            zxp[par][a4][d >> 5][d & 31] = lo_f(v0) + lo_f(v1) + lo_f(v2) + lo_f(v3);
        }
        __syncthreads();                       // (B)

        if (s > 0) {
#pragma unroll
            for (int q4 = 0; q4 < 8; ++q4) {
                const float4 x0 = *reinterpret_cast<const float4*>(&zxp[par][0][p][q4 * 4]);
                const float4 x1 = *reinterpret_cast<const float4*>(&zxp[par][1][p][q4 * 4]);
                const float4 x2 = *reinterpret_cast<const float4*>(&zxp[par][2][p][q4 * 4]);
                const float4 x3 = *reinterpret_cast<const float4*>(&zxp[par][3][p][q4 * 4]);
                const float sx = x0.x + x1.x + x2.x + x3.x;
                const float sy = x0.y + x1.y + x2.y + x3.y;
                const float sz = x0.z + x1.z + x2.z + x3.z;
                const float sw = x0.w + x1.w + x2.w + x3.w;
                acc += sx * wx[q4 * 4 + 0] + sy * wx[q4 * 4 + 1] +
                       sz * wx[q4 * 4 + 2] + sw * wx[q4 * 4 + 3];
            }
            if (w == 0 && tid < D)
                out[(size_t)(s - 1) * D + d] =
                    zxp[par][0][d >> 5][d & 31] + zxp[par][1][d >> 5][d & 31] +
                    zxp[par][2][d >> 5][d & 31] + zxp[par][3][d >> 5][d & 31];
        }

        acc += __shfl_xor(acc, 1);
        acc += __shfl_xor(acc, 2);
        const float zi = __shfl(acc, lb + 0);
        const float zf = __shfl(acc, lb + 4);
        const float zg = __shfl(acc, lb + 8);
        const float zo = __shfl(acc, lb + 12);
        const float cn = fsigm(zf) * creg + fsigm(zi) * ftanh(zg);
        creg = cn;
        const float hn = fsigm(zo) * ftanh(cn);
        if ((tid & 15) == 0) {
            hs_lds[tid >> 4] = hn;
            astore64(&g_hd[(s + 1) & 1][k0 + (tid >> 4)], pack2((u32)(s + 1), hn));
        }
        __syncthreads();                       // (D) hs_lds visible
        if (tid < D) {
            float px = btv;
#pragma unroll
            for (int kk = 0; kk < SLICE; ++kk)
                px += hs_lds[kk] * wpre[kk];
            astore64(&g_xq[(s + 1) & 1][w][d], pack2((u32)(s + 1), px));
        }
    }

    // final reconstruction row x^{T} (tag T, parity 0), summed by wg 0
    if (w == 0) {
        const u32 want = (u32)T;
        u64 v0, v1, v2, v3;
        for (;;) {
            v0 = aload64(&g_xq[0][a4 * 4 + 0][d]);
            v1 = aload64(&g_xq[0][a4 * 4 + 1][d]);
            v2 = aload64(&g_xq[0][a4 * 4 + 2][d]);
            v3 = aload64(&g_xq[0][a4 * 4 + 3][d]);
            if ((hi_t(v0) == want) & (hi_t(v1) == want) &
                (hi_t(v2) == want) & (hi_t(v3) == want)) break;
        }
        zxp[0][a4][d >> 5][d & 31] = lo_f(v0) + lo_f(v1) + lo_f(v2) + lo_f(v3);
        __syncthreads();
        if (tid < D)
            out[(size_t)(T - 1) * D + d] =
                zxp[0][0][d >> 5][d & 31] + zxp[0][1][d >> 5][d & 31] +
                zxp[0][2][d >> 5][d & 31] + zxp[0][3][d >> 5][d & 31];
    }
}

extern "C" void kernel_launch(void* const* d_in, const int* in_sizes, int n_in,
                              void* d_out, int out_size, void* d_ws, size_t ws_size,
                              hipStream_t stream) {
    const float* traj  = (const float*)d_in[0];
    const float* encWi = (const float*)d_in[1];
    const float* encWh = (const float*)d_in[2];
    const float* encbh = (const float*)d_in[3];
    const float* embW  = (const float*)d_in[4];
    const float* embB  = (const float*)d_in[5];
    const float* diW   = (const float*)d_in[6];
    const float* diB   = (const float*)d_in[7];
    const float* decWi = (const float*)d_in[8];
    const float* decWh = (const float*)d_in[9];
    const float* decbh = (const float*)d_in[10];
    const float* doW   = (const float*)d_in[11];
    const float* dob   = (const float*)d_in[12];
    float* out = (float*)d_out;

    k_xp<<<dim3(8, T / TT), dim3(256), 0, stream>>>(traj, encWi, encbh);
    k_enc<<<dim3(NWG), dim3(NTH), 0, stream>>>(encWh);
    k_emb<<<dim3(1), dim3(256), 0, stream>>>(embW, embB, diW, diB, out);
    k_dec<<<dim3(NWG), dim3(NTH), 0, stream>>>(decWi, decWh, decbh, doW, dob, out);
}

// Round 4
// 6069.442 us; speedup vs baseline: 1.1556x; 1.1556x over previous
//
#include <hip/hip_runtime.h>
#include <math.h>

#define T 512
#define D 128
#define H 512
#define EMB 256
#define Z4 2048          // 4*H
#define NWG 16           // workgroups in recurrent kernels
#define SLICE 32         // hidden units per wg (H/NWG)
#define NTH 512          // threads per wg

typedef unsigned long long u64;
typedef unsigned int u32;

// ---- device-global scratch (tags zeroed by k_xp each call) ----
__device__ float g_xp[T * Z4];        // encoder input projections + bh
__device__ u64 g_he[2][H];            // encoder h, packed {tag,val}, slot = tag&1
__device__ u64 g_hd[2][H];            // decoder h, packed
__device__ u64 g_xq[2][NWG][D];       // decoder x partials, packed
__device__ float g_hd0[H];            // decoder initial hidden

__device__ __forceinline__ u64 aload64(const u64* p) {
    return __hip_atomic_load(p, __ATOMIC_RELAXED, __HIP_MEMORY_SCOPE_AGENT);
}
__device__ __forceinline__ void astore64(u64* p, u64 v) {
    __hip_atomic_store(p, v, __ATOMIC_RELAXED, __HIP_MEMORY_SCOPE_AGENT);
}
__device__ __forceinline__ u64 pack2(u32 tag, float v) {
    return ((u64)tag << 32) | (u64)__float_as_uint(v);
}
__device__ __forceinline__ float lo_f(u64 v) { return __uint_as_float((u32)v); }
__device__ __forceinline__ u32 hi_t(u64 v) { return (u32)(v >> 32); }

// fast gates (round 3 proved absmax 3.8e-6 with these; shorter serial chain)
__device__ __forceinline__ float fsigm(float x) {
    x = fminf(fmaxf(x, -30.f), 30.f);
    return __builtin_amdgcn_rcpf(1.f + __expf(-x));
}
__device__ __forceinline__ float ftanh(float x) {
    x = fminf(fmaxf(x, -15.f), 15.f);
    const float e = __expf(2.f * x);
    return (e - 1.f) * __builtin_amdgcn_rcpf(e + 1.f);
}

// raw barrier: drain LDS only, NOT vmem (avoids __syncthreads' vmcnt(0) on
// in-flight prefetches/publishes). LDS handoff correctness: each wave waits
// its own ds ops; sched_barrier(0) fences compiler motion (rule #18).
__device__ __forceinline__ void bar_lds() {
    __builtin_amdgcn_sched_barrier(0);
    asm volatile("s_waitcnt lgkmcnt(0)" ::: "memory");
    __builtin_amdgcn_sched_barrier(0);
    __builtin_amdgcn_s_barrier();
    __builtin_amdgcn_sched_barrier(0);
}

// ---- K1: XP = trajectory @ enc_Wi + enc_bh (parallel) + tag-array zeroing ----
#define TT 16
__global__ __launch_bounds__(256, 1)
void k_xp(const float* __restrict__ traj, const float* __restrict__ Wi,
          const float* __restrict__ bh) {
    const int tid = threadIdx.x;
    if (blockIdx.y == 0) {
        const int fid = blockIdx.x * 256 + tid;       // 0..2047
        if (fid < H) {
            g_he[0][fid] = 0ull; g_he[1][fid] = 0ull;
            g_hd[0][fid] = 0ull; g_hd[1][fid] = 0ull;
        }
        u64* xqf = &g_xq[0][0][0];                    // 2*NWG*D = 4096 entries
        xqf[fid] = 0ull; xqf[fid + 2048] = 0ull;
    }
    const int jc = blockIdx.x;     // 0..7 column chunk
    const int t0 = blockIdx.y * TT;
    const int j  = jc * 256 + tid;

    __shared__ float tl[TT * D];
#pragma unroll
    for (int r = 0; r < (TT * D) / 256; ++r)
        tl[r * 256 + tid] = traj[t0 * D + r * 256 + tid];
    __syncthreads();

    float acc[TT];
#pragma unroll
    for (int tt = 0; tt < TT; ++tt) acc[tt] = 0.f;
    for (int i = 0; i < D; ++i) {
        const float wv = Wi[i * Z4 + j];
#pragma unroll
        for (int tt = 0; tt < TT; ++tt) acc[tt] += tl[tt * D + i] * wv;
    }
    const float bv = bh[j];
#pragma unroll
    for (int tt = 0; tt < TT; ++tt)
        g_xp[(t0 + tt) * Z4 + j] = acc[tt] + bv;
}

// round-2 thread mapping (proven): jl = tid&127 -> gate gt=jl>>5, unit u=jl&31;
// p = tid>>7 (wave-uniform part, h rows [128p,128p+128)); col = gt*H + k0 + u.

// ---- K2: encoder recurrence (16 wgs x 512 threads, weights in regs) ----
__global__ __launch_bounds__(NTH, 1)
void k_enc(const float* __restrict__ Wh) {
    const int w   = blockIdx.x;
    const int tid = threadIdx.x;
    const int jl  = tid & 127;
    const int p   = tid >> 7;
    const int k0  = w * SLICE;
    const int col = (jl >> 5) * H + k0 + (jl & 31);

    float wh[128];
#pragma unroll
    for (int q = 0; q < 128; ++q)
        wh[q] = Wh[(p * 128 + q) * Z4 + col];

    __shared__ float hl[2][H];       // parity double-buffer
    __shared__ float zred[NTH];

    float creg = 0.f;                // cell state (tid < 32)
    // prologue: xp for t=0 (pipelined one step ahead thereafter)
    float xpv = (p == 0) ? g_xp[col] : 0.f;

    for (int t = 0; t < T; ++t) {
        const int par = t & 1;
        if (t > 0) {
            const u32 want = (u32)t;
            const u64* hp = &g_he[par][tid];
            u64 v;
            do { v = aload64(hp); } while (hi_t(v) != want);
            hl[par][tid] = lo_f(v);
        } else {
            hl[par][tid] = 0.f;
        }
        // issue NEXT step's xp now: drains (complete) at next poll's vmcnt(0)
        const int tn = (t + 1 < T) ? t + 1 : T - 1;
        float xpn = (p == 0) ? g_xp[tn * Z4 + col] : 0.f;

        bar_lds();                              // (A) hl ready

        float acc = xpv;
#pragma unroll
        for (int q4 = 0; q4 < 32; ++q4) {
            const float4 hv = *reinterpret_cast<const float4*>(&hl[par][p * 128 + q4 * 4]);
            acc += hv.x * wh[q4 * 4 + 0] + hv.y * wh[q4 * 4 + 1] +
                   hv.z * wh[q4 * 4 + 2] + hv.w * wh[q4 * 4 + 3];
        }
        zred[tid] = acc;
        bar_lds();                              // (B) zred ready

        if (tid < 32) {
            float zi = 0.f, zf = 0.f, zg = 0.f, zo = 0.f;
#pragma unroll
            for (int p4 = 0; p4 < 4; ++p4) {
                zi += zred[p4 * 128 +   0 + tid];
                zf += zred[p4 * 128 +  32 + tid];
                zg += zred[p4 * 128 +  64 + tid];
                zo += zred[p4 * 128 +  96 + tid];
            }
            const float cn = fsigm(zf) * creg + fsigm(zi) * ftanh(zg);
            creg = cn;
            const float hn = fsigm(zo) * ftanh(cn);
            astore64(&g_he[(t + 1) & 1][k0 + tid], pack2((u32)(t + 1), hn));
        }
        // no barrier here: gate threads' zred reads finish before they pass
        // next (A); hl is parity-double-buffered.
        xpv = xpn;
    }
}

// ---- K3: embedding + decoder init (1 wg) ----
__global__ __launch_bounds__(256, 1)
void k_emb(const float* __restrict__ embW, const float* __restrict__ embB,
           const float* __restrict__ diW, const float* __restrict__ diB,
           float* __restrict__ out) {
    const int tid = threadIdx.x;
    __shared__ float h_l[H];
    __shared__ float e_l[EMB];
#pragma unroll
    for (int r = 0; r < H / 256; ++r)
        h_l[r * 256 + tid] = lo_f(g_he[0][r * 256 + tid]);   // tag 512, slot 0
    __syncthreads();

    float acc = embB[tid];
    for (int i = 0; i < H; ++i)
        acc += h_l[i] * embW[i * EMB + tid];
    e_l[tid] = acc;
    out[T * D + tid] = acc;            // embedding output
    __syncthreads();

#pragma unroll
    for (int r = 0; r < H / 256; ++r) {
        const int k = r * 256 + tid;
        float a2 = diB[k];
        for (int e = 0; e < EMB; ++e)
            a2 += e_l[e] * diW[e * H + k];
        g_hd0[k] = a2;
    }
}

// ---- K4: decoder recurrence + per-step output (16 wgs x 512 threads) ----
__global__ __launch_bounds__(NTH, 1)
void k_dec(const float* __restrict__ Wi, const float* __restrict__ Wh,
           const float* __restrict__ bh, const float* __restrict__ Wt,
           const float* __restrict__ bt, float* __restrict__ out) {
    const int w   = blockIdx.x;
    const int tid = threadIdx.x;
    const int jl  = tid & 127;
    const int p   = tid >> 7;        // x rows [32p,32p+32), h rows [128p,128p+128)
    const int k0  = w * SLICE;
    const int col = (jl >> 5) * H + k0 + (jl & 31);
    const int d   = tid & 127;       // x dim for poll/px
    const int a4  = tid >> 7;        // x-partial slot group 0..3

    float wx[32], wh[128];
#pragma unroll
    for (int q = 0; q < 32; ++q)
        wx[q] = Wi[(p * 32 + q) * Z4 + col];
#pragma unroll
    for (int q = 0; q < 128; ++q)
        wh[q] = Wh[(p * 128 + q) * Z4 + col];
    const float bhz = (p == 0) ? bh[col] : 0.f;

    __shared__ float hl[2][H];            // h, parity dbuf
    __shared__ float zxp[2][4][D];        // summed x partials [par][a4][d]
    __shared__ float zred[NTH];
    __shared__ float hs_lds[SLICE];

    float creg = 0.f;

    // prologue: prefetch Wt rows + bt for s=0 (pipelined one step ahead after)
    float wpre[SLICE];
    float btv = 0.f;
    if (tid < D) {
#pragma unroll
        for (int kk = 0; kk < SLICE; ++kk)
            wpre[kk] = Wt[(size_t)(k0 + kk) * D + d];
        if (w == 0) btv = bt[d];
    }

    for (int s = 0; s < T; ++s) {
        const int par = s & 1;

        if (s > 0) {
            const u32 want = (u32)s;
            const u64* hp = &g_hd[par][tid];
            u64 v;
            do { v = aload64(hp); } while (hi_t(v) != want);
            hl[par][tid] = lo_f(v);
        } else {
            hl[par][tid] = g_hd0[tid];
        }
        bar_lds();                              // (A) hl ready

        float acc = bhz;
#pragma unroll
        for (int q4 = 0; q4 < 32; ++q4) {
            const float4 hv = *reinterpret_cast<const float4*>(&hl[par][p * 128 + q4 * 4]);
            acc += hv.x * wh[q4 * 4 + 0] + hv.y * wh[q4 * 4 + 1] +
                   hv.z * wh[q4 * 4 + 2] + hv.w * wh[q4 * 4 + 3];
        }

        // x partials: published ~0.2us after h; polled only now (matvec cover)
        if (s > 0) {
            const u32 want = (u32)s;
            const u64* x0 = &g_xq[par][a4 * 4 + 0][d];
            const u64* x1 = &g_xq[par][a4 * 4 + 1][d];
            const u64* x2 = &g_xq[par][a4 * 4 + 2][d];
            const u64* x3 = &g_xq[par][a4 * 4 + 3][d];
            u64 v0, v1, v2, v3;
            for (;;) {
                v0 = aload64(x0); v1 = aload64(x1);
                v2 = aload64(x2); v3 = aload64(x3);
                if ((hi_t(v0) == want) & (hi_t(v1) == want) &
                    (hi_t(v2) == want) & (hi_t(v3) == want)) break;
            }
            zxp[par][a4][d] = lo_f(v0) + lo_f(v1) + lo_f(v2) + lo_f(v3);
        }
        bar_lds();                              // (B) zxp ready

        if (s > 0) {
#pragma unroll
            for (int q4 = 0; q4 < 8; ++q4) {
                const float4 x0 = *reinterpret_cast<const float4*>(&zxp[par][0][p * 32 + q4 * 4]);
                const float4 x1 = *reinterpret_cast<const float4*>(&zxp[par][1][p * 32 + q4 * 4]);
                const float4 x2 = *reinterpret_cast<const float4*>(&zxp[par][2][p * 32 + q4 * 4]);
                const float4 x3 = *reinterpret_cast<const float4*>(&zxp[par][3][p * 32 + q4 * 4]);
                acc += (x0.x + x1.x + x2.x + x3.x) * wx[q4 * 4 + 0] +
                       (x0.y + x1.y + x2.y + x3.y) * wx[q4 * 4 + 1] +
                       (x0.z + x1.z + x2.z + x3.z) * wx[q4 * 4 + 2] +
                       (x0.w + x1.w + x2.w + x3.w) * wx[q4 * 4 + 3];
            }
            if (w == 0 && tid < D)
                out[(size_t)(s - 1) * D + d] =
                    zxp[par][0][d] + zxp[par][1][d] + zxp[par][2][d] + zxp[par][3][d];
        }
        zred[tid] = acc;
        bar_lds();                              // (C) zred ready

        if (tid < 32) {
            float zi = 0.f, zf = 0.f, zg = 0.f, zo = 0.f;
#pragma unroll
            for (int p4 = 0; p4 < 4; ++p4) {
                zi += zred[p4 * 128 +   0 + tid];
                zf += zred[p4 * 128 +  32 + tid];
                zg += zred[p4 * 128 +  64 + tid];
                zo += zred[p4 * 128 +  96 + tid];
            }
            const float cn = fsigm(zf) * creg + fsigm(zi) * ftanh(zg);
            creg = cn;
            const float hn = fsigm(zo) * ftanh(cn);
            hs_lds[tid] = hn;
            astore64(&g_hd[(s + 1) & 1][k0 + tid], pack2((u32)(s + 1), hn));
        }
        bar_lds();                              // (D) hs_lds ready

        if (tid < D) {
            float px = btv;
#pragma unroll
            for (int kk = 0; kk < SLICE; ++kk)
                px += hs_lds[kk] * wpre[kk];
            astore64(&g_xq[(s + 1) & 1][w][d], pack2((u32)(s + 1), px));
            // prefetch NEXT step's Wt rows + bt into the now-free registers
            const int sn = (s + 1 < T) ? s + 1 : T - 1;
#pragma unroll
            for (int kk = 0; kk < SLICE; ++kk)
                wpre[kk] = Wt[((size_t)sn * H + k0 + kk) * D + d];
            if (w == 0) btv = bt[sn * D + d];
        }
    }

    // final reconstruction row x^{T} (tag T, parity 0), summed by wg 0
    if (w == 0) {
        const u32 want = (u32)T;
        u64 v0, v1, v2, v3;
        for (;;) {
            v0 = aload64(&g_xq[0][a4 * 4 + 0][d]);
            v1 = aload64(&g_xq[0][a4 * 4 + 1][d]);
            v2 = aload64(&g_xq[0][a4 * 4 + 2][d]);
            v3 = aload64(&g_xq[0][a4 * 4 + 3][d]);
            if ((hi_t(v0) == want) & (hi_t(v1) == want) &
                (hi_t(v2) == want) & (hi_t(v3) == want)) break;
        }
        zxp[0][a4][d] = lo_f(v0) + lo_f(v1) + lo_f(v2) + lo_f(v3);
        bar_lds();
        if (tid < D)
            out[(size_t)(T - 1) * D + d] =
                zxp[0][0][d] + zxp[0][1][d] + zxp[0][2][d] + zxp[0][3][d];
    }
}

extern "C" void kernel_launch(void* const* d_in, const int* in_sizes, int n_in,
                              void* d_out, int out_size, void* d_ws, size_t ws_size,
                              hipStream_t stream) {
    const float* traj  = (const float*)d_in[0];
    const float* encWi = (const float*)d_in[1];
    const float* encWh = (const float*)d_in[2];
    const float* encbh = (const float*)d_in[3];
    const float* embW  = (const float*)d_in[4];
    const float* embB  = (const float*)d_in[5];
    const float* diW   = (const float*)d_in[6];
    const float* diB   = (const float*)d_in[7];
    const float* decWi = (const float*)d_in[8];
    const float* decWh = (const float*)d_in[9];
    const float* decbh = (const float*)d_in[10];
    const float* doW   = (const float*)d_in[11];
    const float* dob   = (const float*)d_in[12];
    float* out = (float*)d_out;

    k_xp<<<dim3(8, T / TT), dim3(256), 0, stream>>>(traj, encWi, encbh);
    k_enc<<<dim3(NWG), dim3(NTH), 0, stream>>>(encWh);
    k_emb<<<dim3(1), dim3(256), 0, stream>>>(embW, embB, diW, diB, out);
    k_dec<<<dim3(NWG), dim3(NTH), 0, stream>>>(decWi, decWh, decbh, doW, dob, out);
}

// Round 5
// 2727.722 us; speedup vs baseline: 2.5714x; 2.2251x over previous
//
#include <hip/hip_runtime.h>
#include <math.h>

#define T 512
#define D 128
#define H 512
#define EMB 256
#define Z4 2048          // 4*H
#define NWG 16           // workgroups in recurrent kernels
#define SLICE 32         // hidden units per wg (H/NWG)
#define NTH 512          // threads per wg

typedef unsigned long long u64;
typedef unsigned int u32;

// ---- device-global scratch (tags zeroed by k_xp each call) ----
__device__ float g_xp[T * Z4];        // encoder input projections + bh
__device__ u64 g_he[2][H];            // encoder h, packed {tag,val}, slot = tag&1
__device__ u64 g_hd[2][H];            // decoder h, packed
__device__ u64 g_xq[2][NWG][D];       // decoder x partials, packed
__device__ float g_hd0[H];            // decoder initial hidden

__device__ __forceinline__ u64 aload64(const u64* p) {
    return __hip_atomic_load(p, __ATOMIC_RELAXED, __HIP_MEMORY_SCOPE_AGENT);
}
__device__ __forceinline__ void astore64(u64* p, u64 v) {
    __hip_atomic_store(p, v, __ATOMIC_RELAXED, __HIP_MEMORY_SCOPE_AGENT);
}
__device__ __forceinline__ u64 pack2(u32 tag, float v) {
    return ((u64)tag << 32) | (u64)__float_as_uint(v);
}
__device__ __forceinline__ float lo_f(u64 v) { return __uint_as_float((u32)v); }
__device__ __forceinline__ u32 hi_t(u64 v) { return (u32)(v >> 32); }

// libm gates (round-2 k_dec verbatim)
__device__ __forceinline__ float sigm(float x) { return 1.0f / (1.0f + expf(-x)); }

// fast gates (k_enc only; proven absmax 1.9e-6 in round 4)
__device__ __forceinline__ float fsigm(float x) {
    x = fminf(fmaxf(x, -30.f), 30.f);
    return __builtin_amdgcn_rcpf(1.f + __expf(-x));
}
__device__ __forceinline__ float ftanh(float x) {
    x = fminf(fmaxf(x, -15.f), 15.f);
    const float e = __expf(2.f * x);
    return (e - 1.f) * __builtin_amdgcn_rcpf(e + 1.f);
}

// raw barrier: drain LDS only, NOT vmem (k_enc only; measured good in round 4)
__device__ __forceinline__ void bar_lds() {
    __builtin_amdgcn_sched_barrier(0);
    asm volatile("s_waitcnt lgkmcnt(0)" ::: "memory");
    __builtin_amdgcn_sched_barrier(0);
    __builtin_amdgcn_s_barrier();
    __builtin_amdgcn_sched_barrier(0);
}

// ---- K1: XP = trajectory @ enc_Wi + enc_bh (parallel) + tag-array zeroing ----
#define TT 16
__global__ __launch_bounds__(256, 1)
void k_xp(const float* __restrict__ traj, const float* __restrict__ Wi,
          const float* __restrict__ bh) {
    const int tid = threadIdx.x;
    if (blockIdx.y == 0) {
        const int fid = blockIdx.x * 256 + tid;       // 0..2047
        if (fid < H) {
            g_he[0][fid] = 0ull; g_he[1][fid] = 0ull;
            g_hd[0][fid] = 0ull; g_hd[1][fid] = 0ull;
        }
        u64* xqf = &g_xq[0][0][0];                    // 2*NWG*D = 4096 entries
        xqf[fid] = 0ull; xqf[fid + 2048] = 0ull;
    }
    const int jc = blockIdx.x;     // 0..7 column chunk
    const int t0 = blockIdx.y * TT;
    const int j  = jc * 256 + tid;

    __shared__ float tl[TT * D];
#pragma unroll
    for (int r = 0; r < (TT * D) / 256; ++r)
        tl[r * 256 + tid] = traj[t0 * D + r * 256 + tid];
    __syncthreads();

    float acc[TT];
#pragma unroll
    for (int tt = 0; tt < TT; ++tt) acc[tt] = 0.f;
    for (int i = 0; i < D; ++i) {
        const float wv = Wi[i * Z4 + j];
#pragma unroll
        for (int tt = 0; tt < TT; ++tt) acc[tt] += tl[tt * D + i] * wv;
    }
    const float bv = bh[j];
#pragma unroll
    for (int tt = 0; tt < TT; ++tt)
        g_xp[(t0 + tt) * Z4 + j] = acc[tt] + bv;
}

// ---- K2: encoder recurrence (round-4 version, measured ~1.35us/step) ----
__global__ __launch_bounds__(NTH, 1)
void k_enc(const float* __restrict__ Wh) {
    const int w   = blockIdx.x;
    const int tid = threadIdx.x;
    const int jl  = tid & 127;
    const int p   = tid >> 7;
    const int k0  = w * SLICE;
    const int col = (jl >> 5) * H + k0 + (jl & 31);

    float wh[128];
#pragma unroll
    for (int q = 0; q < 128; ++q)
        wh[q] = Wh[(p * 128 + q) * Z4 + col];

    __shared__ float hl[2][H];       // parity double-buffer
    __shared__ float zred[NTH];

    float creg = 0.f;                // cell state (tid < 32)
    float xpv = (p == 0) ? g_xp[col] : 0.f;

    for (int t = 0; t < T; ++t) {
        const int par = t & 1;
        if (t > 0) {
            const u32 want = (u32)t;
            const u64* hp = &g_he[par][tid];
            u64 v;
            do { v = aload64(hp); } while (hi_t(v) != want);
            hl[par][tid] = lo_f(v);
        } else {
            hl[par][tid] = 0.f;
        }
        const int tn = (t + 1 < T) ? t + 1 : T - 1;
        float xpn = (p == 0) ? g_xp[tn * Z4 + col] : 0.f;

        bar_lds();                              // (A) hl ready

        float acc = xpv;
#pragma unroll
        for (int q4 = 0; q4 < 32; ++q4) {
            const float4 hv = *reinterpret_cast<const float4*>(&hl[par][p * 128 + q4 * 4]);
            acc += hv.x * wh[q4 * 4 + 0] + hv.y * wh[q4 * 4 + 1] +
                   hv.z * wh[q4 * 4 + 2] + hv.w * wh[q4 * 4 + 3];
        }
        zred[tid] = acc;
        bar_lds();                              // (B) zred ready

        if (tid < 32) {
            float zi = 0.f, zf = 0.f, zg = 0.f, zo = 0.f;
#pragma unroll
            for (int p4 = 0; p4 < 4; ++p4) {
                zi += zred[p4 * 128 +   0 + tid];
                zf += zred[p4 * 128 +  32 + tid];
                zg += zred[p4 * 128 +  64 + tid];
                zo += zred[p4 * 128 +  96 + tid];
            }
            const float cn = fsigm(zf) * creg + fsigm(zi) * ftanh(zg);
            creg = cn;
            const float hn = fsigm(zo) * ftanh(cn);
            astore64(&g_he[(t + 1) & 1][k0 + tid], pack2((u32)(t + 1), hn));
        }
        xpv = xpn;
    }
}

// ---- K3: embedding + decoder init (1 wg) ----
__global__ __launch_bounds__(256, 1)
void k_emb(const float* __restrict__ embW, const float* __restrict__ embB,
           const float* __restrict__ diW, const float* __restrict__ diB,
           float* __restrict__ out) {
    const int tid = threadIdx.x;
    __shared__ float h_l[H];
    __shared__ float e_l[EMB];
#pragma unroll
    for (int r = 0; r < H / 256; ++r)
        h_l[r * 256 + tid] = lo_f(g_he[0][r * 256 + tid]);   // tag 512, slot 0
    __syncthreads();

    float acc = embB[tid];
    for (int i = 0; i < H; ++i)
        acc += h_l[i] * embW[i * EMB + tid];
    e_l[tid] = acc;
    out[T * D + tid] = acc;            // embedding output
    __syncthreads();

#pragma unroll
    for (int r = 0; r < H / 256; ++r) {
        const int k = r * 256 + tid;
        float a2 = diB[k];
        for (int e = 0; e < EMB; ++e)
            a2 += e_l[e] * diW[e * H + k];
        g_hd0[k] = a2;
    }
}

// ---- K4: decoder recurrence + per-step output (ROUND-2 VERBATIM, 1776us) ----
__global__ __launch_bounds__(NTH, 1)
void k_dec(const float* __restrict__ Wi, const float* __restrict__ Wh,
           const float* __restrict__ bh, const float* __restrict__ Wt,
           const float* __restrict__ bt, float* __restrict__ out) {
    const int w   = blockIdx.x;
    const int tid = threadIdx.x;
    const int jl  = tid & 127;
    const int p   = tid >> 7;        // x rows [32p,32p+32), h rows [128p,128p+128)
    const int k0  = w * SLICE;
    const int gcol = (jl >> 5) * H + k0 + (jl & 31);
    const int d   = tid & 127;       // for x-partial sum
    const int g4  = tid >> 7;        // partial-slot group 0..3

    float wx[32], wh[128];
#pragma unroll
    for (int q = 0; q < 32; ++q)
        wx[q] = Wi[(p * 32 + q) * Z4 + gcol];
#pragma unroll
    for (int q = 0; q < 128; ++q)
        wh[q] = Wh[(p * 128 + q) * Z4 + gcol];
    const float bhz = (tid < 128) ? bh[(tid >> 5) * H + k0 + (tid & 31)] : 0.f;

    __shared__ float h_lds[H];
    __shared__ float xs_lds[D];
    __shared__ float zred[NTH];
    __shared__ float zfin[128];
    __shared__ float hs_lds[SLICE];

    float creg = 0.f;

    for (int s = 0; s < T; ++s) {
        // prefetch this step's output-weight rows (independent of h)
        float wpre[SLICE];
        float btv = 0.f;
        if (tid < D) {
#pragma unroll
            for (int kk = 0; kk < SLICE; ++kk)
                wpre[kk] = Wt[((size_t)s * H + k0 + kk) * D + d];
            if (w == 0) btv = bt[s * D + d];
        }

        if (s > 0) {
            const u32 want = (u32)s;
            const int par  = s & 1;
            u64 vh, v0, v1, v2, v3;
            for (;;) {
                vh = aload64(&g_hd[par][tid]);
                v0 = aload64(&g_xq[par][g4 * 4 + 0][d]);
                v1 = aload64(&g_xq[par][g4 * 4 + 1][d]);
                v2 = aload64(&g_xq[par][g4 * 4 + 2][d]);
                v3 = aload64(&g_xq[par][g4 * 4 + 3][d]);
                if ((hi_t(vh) == want) & (hi_t(v0) == want) & (hi_t(v1) == want) &
                    (hi_t(v2) == want) & (hi_t(v3) == want)) break;
            }
            h_lds[tid] = lo_f(vh);
            zred[tid]  = lo_f(v0) + lo_f(v1) + lo_f(v2) + lo_f(v3);
            __syncthreads();
            if (tid < D) {
                const float xv = zred[tid] + zred[128 + tid] + zred[256 + tid] + zred[384 + tid];
                xs_lds[tid] = xv;
                if (w == 0) out[(size_t)(s - 1) * D + tid] = xv;
            }
        } else {
            h_lds[tid] = g_hd0[tid];
            if (tid < D) xs_lds[tid] = 0.f;
        }
        __syncthreads();                       // (A)

        float acc = 0.f;
#pragma unroll
        for (int q4 = 0; q4 < 8; ++q4) {
            const float4 xv = *reinterpret_cast<const float4*>(&xs_lds[p * 32 + q4 * 4]);
            acc += xv.x * wx[q4 * 4 + 0] + xv.y * wx[q4 * 4 + 1] +
                   xv.z * wx[q4 * 4 + 2] + xv.w * wx[q4 * 4 + 3];
        }
#pragma unroll
        for (int q4 = 0; q4 < 32; ++q4) {
            const float4 hv = *reinterpret_cast<const float4*>(&h_lds[p * 128 + q4 * 4]);
            acc += hv.x * wh[q4 * 4 + 0] + hv.y * wh[q4 * 4 + 1] +
                   hv.z * wh[q4 * 4 + 2] + hv.w * wh[q4 * 4 + 3];
        }
        zred[tid] = acc;
        __syncthreads();                       // (B)
        if (tid < 128)
            zfin[tid] = zred[tid] + zred[128 + tid] + zred[256 + tid] + zred[384 + tid] + bhz;
        __syncthreads();                       // (C)
        if (tid < SLICE) {
            const float zi = zfin[tid], zf = zfin[32 + tid],
                        zg = zfin[64 + tid], zo = zfin[96 + tid];
            const float cn = sigm(zf) * creg + sigm(zi) * tanhf(zg);
            creg = cn;
            const float hn = sigm(zo) * tanhf(cn);
            hs_lds[tid] = hn;
            astore64(&g_hd[(s + 1) & 1][k0 + tid], pack2((u32)(s + 1), hn));
        }
        __syncthreads();                       // (D) hs_lds visible
        if (tid < D) {
            float px = btv;
#pragma unroll
            for (int kk = 0; kk < SLICE; ++kk)
                px += hs_lds[kk] * wpre[kk];
            astore64(&g_xq[(s + 1) & 1][w][d], pack2((u32)(s + 1), px));
        }
    }

    // final reconstruction row: x^{T} (tag T, slot T&1 == 0), summed by wg 0
    if (w == 0) {
        const u32 want = (u32)T;
        u64 v0, v1, v2, v3;
        for (;;) {
            v0 = aload64(&g_xq[0][g4 * 4 + 0][d]);
            v1 = aload64(&g_xq[0][g4 * 4 + 1][d]);
            v2 = aload64(&g_xq[0][g4 * 4 + 2][d]);
            v3 = aload64(&g_xq[0][g4 * 4 + 3][d]);
            if ((hi_t(v0) == want) & (hi_t(v1) == want) &
                (hi_t(v2) == want) & (hi_t(v3) == want)) break;
        }
        zred[tid] = lo_f(v0) + lo_f(v1) + lo_f(v2) + lo_f(v3);
        __syncthreads();
        if (tid < D)
            out[(size_t)(T - 1) * D + tid] =
                zred[tid] + zred[128 + tid] + zred[256 + tid] + zred[384 + tid];
    }
}

extern "C" void kernel_launch(void* const* d_in, const int* in_sizes, int n_in,
                              void* d_out, int out_size, void* d_ws, size_t ws_size,
                              hipStream_t stream) {
    const float* traj  = (const float*)d_in[0];
    const float* encWi = (const float*)d_in[1];
    const float* encWh = (const float*)d_in[2];
    const float* encbh = (const float*)d_in[3];
    const float* embW  = (const float*)d_in[4];
    const float* embB  = (const float*)d_in[5];
    const float* diW   = (const float*)d_in[6];
    const float* diB   = (const float*)d_in[7];
    const float* decWi = (const float*)d_in[8];
    const float* decWh = (const float*)d_in[9];
    const float* decbh = (const float*)d_in[10];
    const float* doW   = (const float*)d_in[11];
    const float* dob   = (const float*)d_in[12];
    float* out = (float*)d_out;

    k_xp<<<dim3(8, T / TT), dim3(256), 0, stream>>>(traj, encWi, encbh);
    k_enc<<<dim3(NWG), dim3(NTH), 0, stream>>>(encWh);
    k_emb<<<dim3(1), dim3(256), 0, stream>>>(embW, embB, diW, diB, out);
    k_dec<<<dim3(NWG), dim3(NTH), 0, stream>>>(decWi, decWh, decbh, doW, dob, out);
}

// Round 6
// 2609.135 us; speedup vs baseline: 2.6883x; 1.0455x over previous
//
#include <hip/hip_runtime.h>
#include <math.h>

#define T 512
#define D 128
#define H 512
#define EMB 256
#define Z4 2048          // 4*H
#define NWG 16           // workgroups in recurrent kernels
#define SLICE 32         // hidden units per wg (H/NWG)
#define NTH 512          // threads per wg

typedef unsigned long long u64;
typedef unsigned int u32;

// ---- device-global scratch (tags zeroed by k_xp each call) ----
__device__ float g_xp[T * Z4];        // encoder input projections + bh
__device__ u64 g_he[2][H];            // encoder h, packed {tag,val}, slot = tag&1
__device__ u64 g_hd[2][H];            // decoder h, packed
__device__ u64 g_xq[2][NWG][D];       // decoder x partials, packed
__device__ float g_hd0[H];            // decoder initial hidden

__device__ __forceinline__ u64 aload64(const u64* p) {
    return __hip_atomic_load(p, __ATOMIC_RELAXED, __HIP_MEMORY_SCOPE_AGENT);
}
__device__ __forceinline__ void astore64(u64* p, u64 v) {
    __hip_atomic_store(p, v, __ATOMIC_RELAXED, __HIP_MEMORY_SCOPE_AGENT);
}
__device__ __forceinline__ u64 pack2(u32 tag, float v) {
    return ((u64)tag << 32) | (u64)__float_as_uint(v);
}
__device__ __forceinline__ float lo_f(u64 v) { return __uint_as_float((u32)v); }
__device__ __forceinline__ u32 hi_t(u64 v) { return (u32)(v >> 32); }

// fast gates (proven: enc r4/r5 absmax 1.9e-6, dec r3 3.8e-6; threshold 1.6e-2)
__device__ __forceinline__ float fsigm(float x) {
    x = fminf(fmaxf(x, -30.f), 30.f);
    return __builtin_amdgcn_rcpf(1.f + __expf(-x));
}
__device__ __forceinline__ float ftanh(float x) {
    x = fminf(fmaxf(x, -15.f), 15.f);
    const float e = __expf(2.f * x);
    return (e - 1.f) * __builtin_amdgcn_rcpf(e + 1.f);
}

// raw barrier: drain LDS only, NOT vmem (proven in k_enc rounds 4/5)
__device__ __forceinline__ void bar_lds() {
    __builtin_amdgcn_sched_barrier(0);
    asm volatile("s_waitcnt lgkmcnt(0)" ::: "memory");
    __builtin_amdgcn_sched_barrier(0);
    __builtin_amdgcn_s_barrier();
    __builtin_amdgcn_sched_barrier(0);
}

// ---- K1: XP = trajectory @ enc_Wi + enc_bh (parallel) + tag-array zeroing ----
#define TT 16
__global__ __launch_bounds__(256, 1)
void k_xp(const float* __restrict__ traj, const float* __restrict__ Wi,
          const float* __restrict__ bh) {
    const int tid = threadIdx.x;
    if (blockIdx.y == 0) {
        const int fid = blockIdx.x * 256 + tid;       // 0..2047
        if (fid < H) {
            g_he[0][fid] = 0ull; g_he[1][fid] = 0ull;
            g_hd[0][fid] = 0ull; g_hd[1][fid] = 0ull;
        }
        u64* xqf = &g_xq[0][0][0];                    // 2*NWG*D = 4096 entries
        xqf[fid] = 0ull; xqf[fid + 2048] = 0ull;
    }
    const int jc = blockIdx.x;     // 0..7 column chunk
    const int t0 = blockIdx.y * TT;
    const int j  = jc * 256 + tid;

    __shared__ float tl[TT * D];
#pragma unroll
    for (int r = 0; r < (TT * D) / 256; ++r)
        tl[r * 256 + tid] = traj[t0 * D + r * 256 + tid];
    __syncthreads();

    float acc[TT];
#pragma unroll
    for (int tt = 0; tt < TT; ++tt) acc[tt] = 0.f;
    for (int i = 0; i < D; ++i) {
        const float wv = Wi[i * Z4 + j];
#pragma unroll
        for (int tt = 0; tt < TT; ++tt) acc[tt] += tl[tt * D + i] * wv;
    }
    const float bv = bh[j];
#pragma unroll
    for (int tt = 0; tt < TT; ++tt)
        g_xp[(t0 + tt) * Z4 + j] = acc[tt] + bv;
}

// ---- K2: encoder recurrence (round-4/5 version, measured ~1.35us/step) ----
__global__ __launch_bounds__(NTH, 1)
void k_enc(const float* __restrict__ Wh) {
    const int w   = blockIdx.x;
    const int tid = threadIdx.x;
    const int jl  = tid & 127;
    const int p   = tid >> 7;
    const int k0  = w * SLICE;
    const int col = (jl >> 5) * H + k0 + (jl & 31);

    float wh[128];
#pragma unroll
    for (int q = 0; q < 128; ++q)
        wh[q] = Wh[(p * 128 + q) * Z4 + col];

    __shared__ float hl[2][H];       // parity double-buffer
    __shared__ float zred[NTH];

    float creg = 0.f;                // cell state (tid < 32)
    float xpv = (p == 0) ? g_xp[col] : 0.f;

    for (int t = 0; t < T; ++t) {
        const int par = t & 1;
        if (t > 0) {
            const u32 want = (u32)t;
            const u64* hp = &g_he[par][tid];
            u64 v;
            do { v = aload64(hp); } while (hi_t(v) != want);
            hl[par][tid] = lo_f(v);
        } else {
            hl[par][tid] = 0.f;
        }
        const int tn = (t + 1 < T) ? t + 1 : T - 1;
        float xpn = (p == 0) ? g_xp[tn * Z4 + col] : 0.f;

        bar_lds();                              // (A) hl ready

        float acc = xpv;
#pragma unroll
        for (int q4 = 0; q4 < 32; ++q4) {
            const float4 hv = *reinterpret_cast<const float4*>(&hl[par][p * 128 + q4 * 4]);
            acc += hv.x * wh[q4 * 4 + 0] + hv.y * wh[q4 * 4 + 1] +
                   hv.z * wh[q4 * 4 + 2] + hv.w * wh[q4 * 4 + 3];
        }
        zred[tid] = acc;
        bar_lds();                              // (B) zred ready

        if (tid < 32) {
            float zi = 0.f, zf = 0.f, zg = 0.f, zo = 0.f;
#pragma unroll
            for (int p4 = 0; p4 < 4; ++p4) {
                zi += zred[p4 * 128 +   0 + tid];
                zf += zred[p4 * 128 +  32 + tid];
                zg += zred[p4 * 128 +  64 + tid];
                zo += zred[p4 * 128 +  96 + tid];
            }
            const float cn = fsigm(zf) * creg + fsigm(zi) * ftanh(zg);
            creg = cn;
            const float hn = fsigm(zo) * ftanh(cn);
            astore64(&g_he[(t + 1) & 1][k0 + tid], pack2((u32)(t + 1), hn));
        }
        xpv = xpn;
    }
}

// ---- K3: embedding + decoder init (1 wg) ----
__global__ __launch_bounds__(256, 1)
void k_emb(const float* __restrict__ embW, const float* __restrict__ embB,
           const float* __restrict__ diW, const float* __restrict__ diB,
           float* __restrict__ out) {
    const int tid = threadIdx.x;
    __shared__ float h_l[H];
    __shared__ float e_l[EMB];
#pragma unroll
    for (int r = 0; r < H / 256; ++r)
        h_l[r * 256 + tid] = lo_f(g_he[0][r * 256 + tid]);   // tag 512, slot 0
    __syncthreads();

    float acc = embB[tid];
    for (int i = 0; i < H; ++i)
        acc += h_l[i] * embW[i * EMB + tid];
    e_l[tid] = acc;
    out[T * D + tid] = acc;            // embedding output
    __syncthreads();

#pragma unroll
    for (int r = 0; r < H / 256; ++r) {
        const int k = r * 256 + tid;
        float a2 = diB[k];
        for (int e = 0; e < EMB; ++e)
            a2 += e_l[e] * diW[e * H + k];
        g_hd0[k] = a2;
    }
}

// ---- K4: decoder = round-2 structure + enc-proven pair (bar_lds, merged
// 32-thread gate stage, fast gates). Combined poll / top prefetch unchanged.
__global__ __launch_bounds__(NTH, 1)
void k_dec(const float* __restrict__ Wi, const float* __restrict__ Wh,
           const float* __restrict__ bh, const float* __restrict__ Wt,
           const float* __restrict__ bt, float* __restrict__ out) {
    const int w   = blockIdx.x;
    const int tid = threadIdx.x;
    const int jl  = tid & 127;
    const int p   = tid >> 7;        // x rows [32p,32p+32), h rows [128p,128p+128)
    const int k0  = w * SLICE;
    const int gcol = (jl >> 5) * H + k0 + (jl & 31);
    const int d   = tid & 127;       // for x-partial sum
    const int g4  = tid >> 7;        // partial-slot group 0..3

    float wx[32], wh[128];
#pragma unroll
    for (int q = 0; q < 32; ++q)
        wx[q] = Wi[(p * 32 + q) * Z4 + gcol];
#pragma unroll
    for (int q = 0; q < 128; ++q)
        wh[q] = Wh[(p * 128 + q) * Z4 + gcol];
    // per-gate biases for the merged gate stage (tid < 32)
    float bhi = 0.f, bhf = 0.f, bhg = 0.f, bho = 0.f;
    if (tid < SLICE) {
        bhi = bh[0 * H + k0 + tid];
        bhf = bh[1 * H + k0 + tid];
        bhg = bh[2 * H + k0 + tid];
        bho = bh[3 * H + k0 + tid];
    }

    __shared__ float h_lds[H];
    __shared__ float xs_lds[D];
    __shared__ float zred[NTH];
    __shared__ float hs_lds[SLICE];

    float creg = 0.f;

    for (int s = 0; s < T; ++s) {
        // prefetch this step's output-weight rows (independent of h)
        float wpre[SLICE];
        float btv = 0.f;
        if (tid < D) {
#pragma unroll
            for (int kk = 0; kk < SLICE; ++kk)
                wpre[kk] = Wt[((size_t)s * H + k0 + kk) * D + d];
            if (w == 0) btv = bt[s * D + d];
        }

        if (s > 0) {
            const u32 want = (u32)s;
            const int par  = s & 1;
            u64 vh, v0, v1, v2, v3;
            for (;;) {
                vh = aload64(&g_hd[par][tid]);
                v0 = aload64(&g_xq[par][g4 * 4 + 0][d]);
                v1 = aload64(&g_xq[par][g4 * 4 + 1][d]);
                v2 = aload64(&g_xq[par][g4 * 4 + 2][d]);
                v3 = aload64(&g_xq[par][g4 * 4 + 3][d]);
                if ((hi_t(vh) == want) & (hi_t(v0) == want) & (hi_t(v1) == want) &
                    (hi_t(v2) == want) & (hi_t(v3) == want)) break;
            }
            h_lds[tid] = lo_f(vh);
            zred[tid]  = lo_f(v0) + lo_f(v1) + lo_f(v2) + lo_f(v3);
            bar_lds();
            if (tid < D) {
                const float xv = zred[tid] + zred[128 + tid] + zred[256 + tid] + zred[384 + tid];
                xs_lds[tid] = xv;
                if (w == 0) out[(size_t)(s - 1) * D + tid] = xv;
            }
        } else {
            h_lds[tid] = g_hd0[tid];
            if (tid < D) xs_lds[tid] = 0.f;
        }
        bar_lds();                             // (A)

        float acc = 0.f;
#pragma unroll
        for (int q4 = 0; q4 < 8; ++q4) {
            const float4 xv = *reinterpret_cast<const float4*>(&xs_lds[p * 32 + q4 * 4]);
            acc += xv.x * wx[q4 * 4 + 0] + xv.y * wx[q4 * 4 + 1] +
                   xv.z * wx[q4 * 4 + 2] + xv.w * wx[q4 * 4 + 3];
        }
#pragma unroll
        for (int q4 = 0; q4 < 32; ++q4) {
            const float4 hv = *reinterpret_cast<const float4*>(&h_lds[p * 128 + q4 * 4]);
            acc += hv.x * wh[q4 * 4 + 0] + hv.y * wh[q4 * 4 + 1] +
                   hv.z * wh[q4 * 4 + 2] + hv.w * wh[q4 * 4 + 3];
        }
        zred[tid] = acc;
        bar_lds();                             // (B)

        if (tid < SLICE) {                     // merged zfin+gates (enc-proven)
            float zi = bhi, zf = bhf, zg = bhg, zo = bho;
#pragma unroll
            for (int p4 = 0; p4 < 4; ++p4) {
                zi += zred[p4 * 128 +   0 + tid];
                zf += zred[p4 * 128 +  32 + tid];
                zg += zred[p4 * 128 +  64 + tid];
                zo += zred[p4 * 128 +  96 + tid];
            }
            const float cn = fsigm(zf) * creg + fsigm(zi) * ftanh(zg);
            creg = cn;
            const float hn = fsigm(zo) * ftanh(cn);
            hs_lds[tid] = hn;
            astore64(&g_hd[(s + 1) & 1][k0 + tid], pack2((u32)(s + 1), hn));
        }
        bar_lds();                             // (C) hs_lds visible

        if (tid < D) {
            float px = btv;
#pragma unroll
            for (int kk = 0; kk < SLICE; ++kk)
                px += hs_lds[kk] * wpre[kk];
            astore64(&g_xq[(s + 1) & 1][w][d], pack2((u32)(s + 1), px));
        }
    }

    // final reconstruction row: x^{T} (tag T, slot T&1 == 0), summed by wg 0
    if (w == 0) {
        const u32 want = (u32)T;
        u64 v0, v1, v2, v3;
        for (;;) {
            v0 = aload64(&g_xq[0][g4 * 4 + 0][d]);
            v1 = aload64(&g_xq[0][g4 * 4 + 1][d]);
            v2 = aload64(&g_xq[0][g4 * 4 + 2][d]);
            v3 = aload64(&g_xq[0][g4 * 4 + 3][d]);
            if ((hi_t(v0) == want) & (hi_t(v1) == want) &
                (hi_t(v2) == want) & (hi_t(v3) == want)) break;
        }
        zred[tid] = lo_f(v0) + lo_f(v1) + lo_f(v2) + lo_f(v3);
        bar_lds();
        if (tid < D)
            out[(size_t)(T - 1) * D + tid] =
                zred[tid] + zred[128 + tid] + zred[256 + tid] + zred[384 + tid];
    }
}

extern "C" void kernel_launch(void* const* d_in, const int* in_sizes, int n_in,
                              void* d_out, int out_size, void* d_ws, size_t ws_size,
                              hipStream_t stream) {
    const float* traj  = (const float*)d_in[0];
    const float* encWi = (const float*)d_in[1];
    const float* encWh = (const float*)d_in[2];
    const float* encbh = (const float*)d_in[3];
    const float* embW  = (const float*)d_in[4];
    const float* embB  = (const float*)d_in[5];
    const float* diW   = (const float*)d_in[6];
    const float* diB   = (const float*)d_in[7];
    const float* decWi = (const float*)d_in[8];
    const float* decWh = (const float*)d_in[9];
    const float* decbh = (const float*)d_in[10];
    const float* doW   = (const float*)d_in[11];
    const float* dob   = (const float*)d_in[12];
    float* out = (float*)d_out;

    k_xp<<<dim3(8, T / TT), dim3(256), 0, stream>>>(traj, encWi, encbh);
    k_enc<<<dim3(NWG), dim3(NTH), 0, stream>>>(encWh);
    k_emb<<<dim3(1), dim3(256), 0, stream>>>(embW, embB, diW, diB, out);
    k_dec<<<dim3(NWG), dim3(NTH), 0, stream>>>(decWi, decWh, decbh, doW, dob, out);
}